// Round 4
// baseline (207.716 us; speedup 1.0000x reference)
//
#include <hip/hip_runtime.h>
#include <hip/hip_bf16.h>
#include <cstdint>

#define B_ 8
#define C_ 256
#define N_ 4096

typedef __bf16 bf16;
typedef __bf16 bf16x8 __attribute__((ext_vector_type(8)));
typedef float f32x4 __attribute__((ext_vector_type(4)));
typedef float f32x16 __attribute__((ext_vector_type(16)));
typedef unsigned int u32;

__device__ __forceinline__ void async_ld16(const void* g, void* l) {
  __builtin_amdgcn_global_load_lds(
      (const __attribute__((address_space(1))) void*)g,
      (__attribute__((address_space(3))) void*)l, 16, 0, 0);
}

__device__ __forceinline__ float bh2f(unsigned short u) {
  union { u32 i; float f; } x; x.i = ((u32)u) << 16; return x.f;
}
__device__ __forceinline__ unsigned short f2bh(float f) {
  union { float f; u32 i; } x; x.f = f;
  u32 i = x.i + 0x7fffu + ((x.i >> 16) & 1u);
  return (unsigned short)(i >> 16);
}

// Per-wave dtype sniff (fp32 vs bf16 buffer), validated R2/R3.
__device__ __forceinline__ bool wave_sniff_fp32(const unsigned short* p) {
  int l = threadIdx.x & 63;
  unsigned short u = p[2 * l];
  int e = (u >> 7) & 0xff;
  unsigned long long m = __ballot(e >= 112 && e <= 142);
  return __popcll(m) < 32;
}

// ---------------- kernel 0 (merged): blocks 0..255 = Mt; 256.. = transpose ----------
__global__ __launch_bounds__(256) void k_pre(const void* __restrict__ Wqv,
                                             const void* __restrict__ Wkv,
                                             const void* __restrict__ Fv,
                                             unsigned short* __restrict__ Mt,
                                             unsigned short* __restrict__ Ft) {
  __shared__ float wkcol[C_];
  __shared__ unsigned short tile[64 * 66];
  int bid = blockIdx.x;
  int t = threadIdx.x;
  if (bid < 256) {
    bool fq = wave_sniff_fp32((const unsigned short*)Wqv);
    bool fk = wave_sniff_fp32((const unsigned short*)Wkv);
    int d = bid, c = t;
    if (fk)
      wkcol[c] = ((const float*)Wkv)[c * C_ + d];
    else
      wkcol[c] = bh2f(((const unsigned short*)Wkv)[c * C_ + d]);
    __syncthreads();
    float acc = 0.f;
    if (fq) {
      for (int e0 = 0; e0 < C_; e0 += 16) {
        float wq[16];
#pragma unroll
        for (int j = 0; j < 16; ++j) wq[j] = ((const float*)Wqv)[(e0 + j) * C_ + c];
#pragma unroll
        for (int j = 0; j < 16; ++j) acc += wkcol[e0 + j] * wq[j];
      }
    } else {
      for (int e0 = 0; e0 < C_; e0 += 16) {
        float wq[16];
#pragma unroll
        for (int j = 0; j < 16; ++j) wq[j] = bh2f(((const unsigned short*)Wqv)[(e0 + j) * C_ + c]);
#pragma unroll
        for (int j = 0; j < 16; ++j) acc += wkcol[e0 + j] * wq[j];
      }
    }
    Mt[(size_t)d * C_ + c] = f2bh(acc);
    return;
  }
  bool f32 = wave_sniff_fp32((const unsigned short*)Fv);
  int id = bid - 256;
  int n0 = (id & 63) * 64, c0 = ((id >> 6) & 3) * 64, b = id >> 8;
#pragma unroll
  for (int p = 0; p < 2; ++p) {
    int c = (t >> 3) + 32 * p;
    int n = (t & 7) * 8;
    size_t off = (size_t)(b * C_ + c0 + c) * N_ + n0 + n;
    unsigned short vals[8];
    if (f32) {
      const float* src = (const float*)Fv + off;
      float4 v0 = *(const float4*)(src);
      float4 v1 = *(const float4*)(src + 4);
      vals[0] = f2bh(v0.x); vals[1] = f2bh(v0.y); vals[2] = f2bh(v0.z); vals[3] = f2bh(v0.w);
      vals[4] = f2bh(v1.x); vals[5] = f2bh(v1.y); vals[6] = f2bh(v1.z); vals[7] = f2bh(v1.w);
    } else {
      uint4 v = *(const uint4*)((const unsigned short*)Fv + off);
      vals[0] = (unsigned short)(v.x & 0xffffu); vals[1] = (unsigned short)(v.x >> 16);
      vals[2] = (unsigned short)(v.y & 0xffffu); vals[3] = (unsigned short)(v.y >> 16);
      vals[4] = (unsigned short)(v.z & 0xffffu); vals[5] = (unsigned short)(v.z >> 16);
      vals[6] = (unsigned short)(v.w & 0xffffu); vals[7] = (unsigned short)(v.w >> 16);
    }
#pragma unroll
    for (int s = 0; s < 8; ++s) tile[c * 66 + n + s] = vals[s];
  }
  __syncthreads();
  // widened output — thread owns (n, 8-c octet), 2 uint4 stores (R12-validated)
#pragma unroll
  for (int p = 0; p < 2; ++p) {
    int n = (t >> 3) + 32 * p;
    int c8 = (t & 7) * 8;
    u32 o[4];
#pragma unroll
    for (int k = 0; k < 4; ++k) {
      unsigned short lo = tile[(c8 + 2 * k) * 66 + n];
      unsigned short hi = tile[(c8 + 2 * k + 1) * 66 + n];
      o[k] = ((u32)hi << 16) | lo;
    }
    uint4 ov; ov.x = o[0]; ov.y = o[1]; ov.z = o[2]; ov.w = o[3];
    *(uint4*)(Ft + ((size_t)(b * N_ + n0 + n) * C_ + c0 + c8)) = ov;
  }
}

// ---------------- kernel 2: G[b,n,d] = sum_c Ft[b,n,c] * Mt[d,c] ----------------
// 64n x 128d tiles, 32KB LDS, grid 1024, 4 blocks/CU (R9-measured config).
// R13: epilogue round-trips C through LDS (reusing As) -> 4 coalesced uint4
// stores/thread instead of 32 scalar 2B stores.
__global__ __launch_bounds__(256, 4) void k_proj(const bf16* __restrict__ Ft,
                                                 const bf16* __restrict__ Mt,
                                                 bf16* __restrict__ G) {
  __shared__ bf16 As[8 * 64 * 32];  // chunk kc at kc*2048; [row][32c] swizzled
  int n0 = blockIdx.x * 64;
  int b = blockIdx.y;
  int d0 = blockIdx.z * 128;
  int t = threadIdx.x, w = t >> 6, l = t & 63;
  int lr = l & 15, lq = l >> 4;
  int wn = w * 32;
  const size_t fbase = (size_t)b * N_ * C_;

  int srow = t >> 2;
  int schunk = ((t & 3) ^ ((t >> 3) & 3)) * 8;
#pragma unroll
  for (int kc = 0; kc < 8; ++kc)
    async_ld16(Ft + fbase + (size_t)(n0 + srow) * C_ + kc * 32 + schunk,
               As + kc * 2048 + t * 8);

  bf16x8 bb[2][8];
#pragma unroll
  for (int j = 0; j < 2; ++j)
#pragma unroll
    for (int kc = 0; kc < 8; ++kc)
      bb[j][kc] = *(const bf16x8*)(Mt + (size_t)(d0 + wn + 16 * j + lr) * C_ + kc * 32 + lq * 8);

  __syncthreads();  // vmcnt drained + barrier
  int rchunk = (lq ^ ((lr >> 1) & 3)) * 8;
  f32x4 acc[4][2] = {};
#pragma unroll
  for (int kc = 0; kc < 8; ++kc) {
#pragma unroll
    for (int i = 0; i < 4; ++i) {
      bf16x8 a = *(const bf16x8*)(As + kc * 2048 + (16 * i + lr) * 32 + rchunk);
#pragma unroll
      for (int j = 0; j < 2; ++j)
        acc[i][j] = __builtin_amdgcn_mfma_f32_16x16x32_bf16(a, bb[j][kc], acc[i][j], 0, 0, 0);
    }
  }
  __syncthreads();  // all As reads complete; reuse As as C-staging
  // Cs: [64 rows][136 stride] u16 (272B rows: 16B-aligned, rows 4 dwords apart
  // -> scatter writes max 2-way bank aliasing = free per m136)
  unsigned short* Cs = (unsigned short*)As;
#pragma unroll
  for (int i = 0; i < 4; ++i)
#pragma unroll
    for (int j = 0; j < 2; ++j)
#pragma unroll
      for (int r = 0; r < 4; ++r)
        Cs[(16 * i + lq * 4 + r) * 136 + wn + 16 * j + lr] = f2bh(acc[i][j][r]);
  __syncthreads();
#pragma unroll
  for (int p = 0; p < 4; ++p) {
    int idx = p * 256 + t;
    int row = idx >> 4, c8 = idx & 15;
    uint4 v = *(const uint4*)(Cs + row * 136 + c8 * 8);
    *(uint4*)(G + fbase + (size_t)(n0 + row) * C_ + d0 + c8 * 8) = v;
  }
}

// ---------------- kernel 3: attention row sums + diagonal ------------------------
// R17: 32x32x16 MFMA shape (was 16x16x32). Same FLOPs and LDS traffic, but:
// MFMA instr count HALVES (16 vs 32 per wave-iter -> issue-slot relief; R1-R3
// showed VALU+MFMA issue jointly saturated at ~78%) and the 32x32 pipe runs at
// 2495 vs 2075 TF (floor 33 -> 27.5us). Two k-split acc chains (accA/accB) avoid
// a 16-deep dependency chain. Registers: a[16]=64 (AGPR) + acc 32 + VGPR ~60 ->
// ~156 total -> 3 waves/SIMD, same as R1's measured occupancy. Pipeline = R1's
// best 2-phase dbuf (R3 ring was no better). B-read under the R9 swizzle is
// conflict-free by 8-lane-phase analysis (same permutation class as R1's).
// Layouts: A row=l&31, k=(l>>5)*8+e; B col=l&31 dual; D col=l&31,
// row=(r&3)+8*(r>>2)+4*(l>>5) [m74/m101].
__global__ __launch_bounds__(256, 4) void k_attn(const bf16* __restrict__ G,
                                                 const bf16* __restrict__ Ft,
                                                 float* __restrict__ snn,
                                                 float* __restrict__ lsum) {
  __shared__ bf16 Ks[2][32 * 256];  // 2 x 16 KB double buffer; kc32-chunk at kc*1024
  int bid = blockIdx.x;
  int b = bid & 7, q = (bid >> 3) & 3, ntile = bid >> 5;
  int n0 = ntile * 128;
  int t = threadIdx.x, w = t >> 6, l = t & 63;
  int lrow = l & 31, lhi = l >> 5;
  int wrow = w * 32;
  const size_t gbase = (size_t)b * N_ * C_;

  // A-frags: lane holds G[n0+wrow+lrow][kc*16 + lhi*8 .. +8)
  bf16x8 a[16];
#pragma unroll
  for (int kc = 0; kc < 16; ++kc)
    a[kc] = *(const bf16x8*)(G + gbase + (size_t)(n0 + wrow + lrow) * C_ + kc * 16 + lhi * 8);

  float part[16];
#pragma unroll
  for (int s = 0; s < 16; ++s) part[s] = 0.f;

  int m_base = q * 1024;
  bool has_diag = (q == (ntile >> 3));
  int dit_it = (ntile & 7) * 4 + w;  // iter whose m-tile holds this wave's diagonal

  // staging offsets: 4 x 16B per thread per 32-row tile (16KB = 1024 x 16B)
  int soff[4];
#pragma unroll
  for (int p = 0; p < 4; ++p) {
    int flat = p * 256 + t;
    int kc = flat >> 7;
    int r = (flat >> 2) & 31;
    int col8 = flat & 3;
    soff[p] = r * C_ + kc * 32 + ((col8 ^ ((r >> 1) & 3)) * 8);
  }
  int sw = (lrow >> 1) & 3;

  // prologue: stage tile 0 into buf 0
#pragma unroll
  for (int p = 0; p < 4; ++p)
    async_ld16(Ft + gbase + (size_t)m_base * C_ + soff[p],
               (bf16*)Ks + (p * 256 + t) * 8);
  asm volatile("s_waitcnt vmcnt(0)" ::: "memory");
  __builtin_amdgcn_s_barrier();

  for (int it = 0; it < 32; ++it) {
    int cur = it & 1;
    if (it < 31) {
      int m0 = m_base + (it + 1) * 32;
#pragma unroll
      for (int p = 0; p < 4; ++p)
        async_ld16(Ft + gbase + (size_t)m0 * C_ + soff[p],
                   (bf16*)Ks + (cur ^ 1) * 8192 + (p * 256 + t) * 8);
    }
    const bf16* ks = (const bf16*)Ks + cur * 8192;
    f32x16 accA = {}, accB = {};
    __builtin_amdgcn_s_setprio(1);
#pragma unroll
    for (int kk = 0; kk < 8; ++kk) {
      const bf16* base = ks + kk * 1024 + lrow * 32;
      bf16x8 b0 = *(const bf16x8*)(base + ((lhi ^ sw) * 8));        // k-chunk 2kk
      bf16x8 b1 = *(const bf16x8*)(base + (((2 + lhi) ^ sw) * 8));  // k-chunk 2kk+1
      accA = __builtin_amdgcn_mfma_f32_32x32x16_bf16(a[2 * kk], b0, accA, 0, 0, 0);
      accB = __builtin_amdgcn_mfma_f32_32x32x16_bf16(a[2 * kk + 1], b1, accB, 0, 0, 0);
    }
    __builtin_amdgcn_s_setprio(0);

    bool dit = has_diag && (it == dit_it);
#pragma unroll
    for (int r = 0; r < 16; ++r) {
      float e = __expf(accA[r] + accB[r]);
      part[r] += e;
      if (dit) {
        int rloc = (r & 3) + 8 * (r >> 2) + 4 * lhi;
        if (lrow == rloc) snn[b * N_ + n0 + wrow + rloc] = e;
      }
    }
    if (it < 31) {
      asm volatile("s_waitcnt vmcnt(0)" ::: "memory");
      __builtin_amdgcn_s_barrier();
    }
  }

  // row-sum: cols of a row live in one 32-lane half at fixed reg r
#pragma unroll
  for (int r = 0; r < 16; ++r) {
    float v = part[r];
    v += __shfl_xor(v, 1);
    v += __shfl_xor(v, 2);
    v += __shfl_xor(v, 4);
    v += __shfl_xor(v, 8);
    v += __shfl_xor(v, 16);
    part[r] = v;
  }
  if (lrow == 0) {
#pragma unroll
    for (int r = 0; r < 16; ++r) {
      int rloc = (r & 3) + 8 * (r >> 2) + 4 * lhi;
      lsum[((size_t)q * B_ + b) * N_ + n0 + wrow + rloc] = part[r];
    }
  }
}

// ---------------- kernel 4: out = F * snn/(sum_q lsum * (1+1e-8)) ----------------
__global__ __launch_bounds__(256) void k_scale(const void* __restrict__ Fv,
                                               const float* __restrict__ snn,
                                               const float* __restrict__ lsum,
                                               void* __restrict__ Outv) {
  bool f32 = wave_sniff_fp32((const unsigned short*)Fv);
  int g = blockIdx.x * 256 + threadIdx.x;
  size_t base = (size_t)g * 8;
  int n = (int)(base & (N_ - 1));
  int b = (int)(base >> 20);
  float4 s0 = *(const float4*)(snn + (size_t)b * N_ + n);
  float4 s1 = *(const float4*)(snn + (size_t)b * N_ + n + 4);
  float ls[8];
#pragma unroll
  for (int k = 0; k < 8; ++k) ls[k] = 0.f;
#pragma unroll
  for (int p = 0; p < 4; ++p) {
    float4 l0 = *(const float4*)(lsum + ((size_t)p * B_ + b) * N_ + n);
    float4 l1 = *(const float4*)(lsum + ((size_t)p * B_ + b) * N_ + n + 4);
    ls[0] += l0.x; ls[1] += l0.y; ls[2] += l0.z; ls[3] += l0.w;
    ls[4] += l1.x; ls[5] += l1.y; ls[6] += l1.z; ls[7] += l1.w;
  }
  const float c1 = 1.0f + 1e-8f;
  float dd[8];
  dd[0] = s0.x / (ls[0] * c1); dd[1] = s0.y / (ls[1] * c1);
  dd[2] = s0.z / (ls[2] * c1); dd[3] = s0.w / (ls[3] * c1);
  dd[4] = s1.x / (ls[4] * c1); dd[5] = s1.y / (ls[5] * c1);
  dd[6] = s1.z / (ls[6] * c1); dd[7] = s1.w / (ls[7] * c1);
  if (f32) {
    const float* F = (const float*)Fv + base;
    float* O = (float*)Outv + base;
    float4 a0 = *(const float4*)(F);
    float4 a1 = *(const float4*)(F + 4);
    float4 o0, o1;
    o0.x = a0.x * dd[0]; o0.y = a0.y * dd[1]; o0.z = a0.z * dd[2]; o0.w = a0.w * dd[3];
    o1.x = a1.x * dd[4]; o1.y = a1.y * dd[5]; o1.z = a1.z * dd[6]; o1.w = a1.w * dd[7];
    *(float4*)(O) = o0;
    *(float4*)(O + 4) = o1;
  } else {
    uint4 v = *(const uint4*)((const unsigned short*)Fv + base);
    u32 vv[4] = {v.x, v.y, v.z, v.w};
    u32 o[4];
#pragma unroll
    for (int k = 0; k < 4; ++k) {
      float lo = bh2f((unsigned short)(vv[k] & 0xffffu)) * dd[2 * k];
      float hi = bh2f((unsigned short)(vv[k] >> 16)) * dd[2 * k + 1];
      o[k] = ((u32)f2bh(hi) << 16) | f2bh(lo);
    }
    uint4 ov; ov.x = o[0]; ov.y = o[1]; ov.z = o[2]; ov.w = o[3];
    *(uint4*)((unsigned short*)Outv + base) = ov;
  }
}

extern "C" void kernel_launch(void* const* d_in, const int* in_sizes, int n_in,
                              void* d_out, int out_size, void* d_ws, size_t ws_size,
                              hipStream_t stream) {
  (void)in_sizes; (void)n_in; (void)out_size; (void)ws_size;
  const void* F = d_in[0];
  const void* Wq = d_in[1];
  const void* Wk = d_in[2];
  char* ws = (char*)d_ws;
  bf16* Ft = (bf16*)(ws);                         // 16 MiB
  bf16* G = (bf16*)(ws + (16u << 20));            // 16 MiB
  char* tail = ws + (32u << 20);
  float* snn = (float*)(tail);                    // 128 KiB
  float* lsum = (float*)(tail + 131072);          // 512 KiB (4 partials)
  bf16* Mt = (bf16*)(tail + 131072 + 524288);     // 128 KiB

  k_pre<<<256 + 2048, 256, 0, stream>>>(Wq, Wk, F, (unsigned short*)Mt, (unsigned short*)Ft);
  k_proj<<<dim3(N_ / 64, B_, 2), 256, 0, stream>>>(Ft, Mt, G);
  k_attn<<<1024, 256, 0, stream>>>(G, Ft, snn, lsum);
  k_scale<<<(B_ * C_ * N_ / 8) / 256, 256, 0, stream>>>(F, snn, lsum, d_out);
}

// Round 5
// 169.810 us; speedup vs baseline: 1.2232x; 1.2232x over previous
//
#include <hip/hip_runtime.h>
#include <hip/hip_bf16.h>
#include <cstdint>

#define B_ 8
#define C_ 256
#define N_ 4096

typedef __bf16 bf16;
typedef __bf16 bf16x8 __attribute__((ext_vector_type(8)));
typedef float f32x4 __attribute__((ext_vector_type(4)));
typedef unsigned int u32;

__device__ __forceinline__ void async_ld16(const void* g, void* l) {
  __builtin_amdgcn_global_load_lds(
      (const __attribute__((address_space(1))) void*)g,
      (__attribute__((address_space(3))) void*)l, 16, 0, 0);
}

__device__ __forceinline__ float bh2f(unsigned short u) {
  union { u32 i; float f; } x; x.i = ((u32)u) << 16; return x.f;
}
__device__ __forceinline__ unsigned short f2bh(float f) {
  union { float f; u32 i; } x; x.f = f;
  u32 i = x.i + 0x7fffu + ((x.i >> 16) & 1u);
  return (unsigned short)(i >> 16);
}

// Per-wave dtype sniff (fp32 vs bf16 buffer), validated R2/R3.
__device__ __forceinline__ bool wave_sniff_fp32(const unsigned short* p) {
  int l = threadIdx.x & 63;
  unsigned short u = p[2 * l];
  int e = (u >> 7) & 0xff;
  unsigned long long m = __ballot(e >= 112 && e <= 142);
  return __popcll(m) < 32;
}

// ---------------- kernel 0 (merged): blocks 0..255 = Mt; 256.. = transpose ----------
// R18: Mt pre-scaled by log2(e) so k_attn uses raw v_exp_f32 (exp2) -- saves one
// v_mul per logit element (exp(S) == 2^(S*log2e), numerically identical).
__global__ __launch_bounds__(256) void k_pre(const void* __restrict__ Wqv,
                                             const void* __restrict__ Wkv,
                                             const void* __restrict__ Fv,
                                             unsigned short* __restrict__ Mt,
                                             unsigned short* __restrict__ Ft) {
  __shared__ float wkcol[C_];
  __shared__ unsigned short tile[64 * 66];
  int bid = blockIdx.x;
  int t = threadIdx.x;
  if (bid < 256) {
    bool fq = wave_sniff_fp32((const unsigned short*)Wqv);
    bool fk = wave_sniff_fp32((const unsigned short*)Wkv);
    int d = bid, c = t;
    if (fk)
      wkcol[c] = ((const float*)Wkv)[c * C_ + d];
    else
      wkcol[c] = bh2f(((const unsigned short*)Wkv)[c * C_ + d]);
    __syncthreads();
    float acc = 0.f;
    if (fq) {
      for (int e0 = 0; e0 < C_; e0 += 16) {
        float wq[16];
#pragma unroll
        for (int j = 0; j < 16; ++j) wq[j] = ((const float*)Wqv)[(e0 + j) * C_ + c];
#pragma unroll
        for (int j = 0; j < 16; ++j) acc += wkcol[e0 + j] * wq[j];
      }
    } else {
      for (int e0 = 0; e0 < C_; e0 += 16) {
        float wq[16];
#pragma unroll
        for (int j = 0; j < 16; ++j) wq[j] = bh2f(((const unsigned short*)Wqv)[(e0 + j) * C_ + c]);
#pragma unroll
        for (int j = 0; j < 16; ++j) acc += wkcol[e0 + j] * wq[j];
      }
    }
    Mt[(size_t)d * C_ + c] = f2bh(acc * 1.44269504f);  // log2(e) fold
    return;
  }
  bool f32 = wave_sniff_fp32((const unsigned short*)Fv);
  int id = bid - 256;
  int n0 = (id & 63) * 64, c0 = ((id >> 6) & 3) * 64, b = id >> 8;
#pragma unroll
  for (int p = 0; p < 2; ++p) {
    int c = (t >> 3) + 32 * p;
    int n = (t & 7) * 8;
    size_t off = (size_t)(b * C_ + c0 + c) * N_ + n0 + n;
    unsigned short vals[8];
    if (f32) {
      const float* src = (const float*)Fv + off;
      float4 v0 = *(const float4*)(src);
      float4 v1 = *(const float4*)(src + 4);
      vals[0] = f2bh(v0.x); vals[1] = f2bh(v0.y); vals[2] = f2bh(v0.z); vals[3] = f2bh(v0.w);
      vals[4] = f2bh(v1.x); vals[5] = f2bh(v1.y); vals[6] = f2bh(v1.z); vals[7] = f2bh(v1.w);
    } else {
      uint4 v = *(const uint4*)((const unsigned short*)Fv + off);
      vals[0] = (unsigned short)(v.x & 0xffffu); vals[1] = (unsigned short)(v.x >> 16);
      vals[2] = (unsigned short)(v.y & 0xffffu); vals[3] = (unsigned short)(v.y >> 16);
      vals[4] = (unsigned short)(v.z & 0xffffu); vals[5] = (unsigned short)(v.z >> 16);
      vals[6] = (unsigned short)(v.w & 0xffffu); vals[7] = (unsigned short)(v.w >> 16);
    }
#pragma unroll
    for (int s = 0; s < 8; ++s) tile[c * 66 + n + s] = vals[s];
  }
  __syncthreads();
  // widened output — thread owns (n, 8-c octet), 2 uint4 stores (R12-validated)
#pragma unroll
  for (int p = 0; p < 2; ++p) {
    int n = (t >> 3) + 32 * p;
    int c8 = (t & 7) * 8;
    u32 o[4];
#pragma unroll
    for (int k = 0; k < 4; ++k) {
      unsigned short lo = tile[(c8 + 2 * k) * 66 + n];
      unsigned short hi = tile[(c8 + 2 * k + 1) * 66 + n];
      o[k] = ((u32)hi << 16) | lo;
    }
    uint4 ov; ov.x = o[0]; ov.y = o[1]; ov.z = o[2]; ov.w = o[3];
    *(uint4*)(Ft + ((size_t)(b * N_ + n0 + n) * C_ + c0 + c8)) = ov;
  }
}

// ---------------- kernel 2: G[b,n,d] = sum_c Ft[b,n,c] * Mt[d,c] ----------------
// 64n x 128d tiles, 32KB LDS, grid 1024, 4 blocks/CU (R9-measured config).
// R13: epilogue round-trips C through LDS (reusing As) -> 4 coalesced uint4
// stores/thread instead of 32 scalar 2B stores.
__global__ __launch_bounds__(256, 4) void k_proj(const bf16* __restrict__ Ft,
                                                 const bf16* __restrict__ Mt,
                                                 bf16* __restrict__ G) {
  __shared__ bf16 As[8 * 64 * 32];  // chunk kc at kc*2048; [row][32c] swizzled
  int n0 = blockIdx.x * 64;
  int b = blockIdx.y;
  int d0 = blockIdx.z * 128;
  int t = threadIdx.x, w = t >> 6, l = t & 63;
  int lr = l & 15, lq = l >> 4;
  int wn = w * 32;
  const size_t fbase = (size_t)b * N_ * C_;

  int srow = t >> 2;
  int schunk = ((t & 3) ^ ((t >> 3) & 3)) * 8;
#pragma unroll
  for (int kc = 0; kc < 8; ++kc)
    async_ld16(Ft + fbase + (size_t)(n0 + srow) * C_ + kc * 32 + schunk,
               As + kc * 2048 + t * 8);

  bf16x8 bb[2][8];
#pragma unroll
  for (int j = 0; j < 2; ++j)
#pragma unroll
    for (int kc = 0; kc < 8; ++kc)
      bb[j][kc] = *(const bf16x8*)(Mt + (size_t)(d0 + wn + 16 * j + lr) * C_ + kc * 32 + lq * 8);

  __syncthreads();  // vmcnt drained + barrier
  int rchunk = (lq ^ ((lr >> 1) & 3)) * 8;
  f32x4 acc[4][2] = {};
#pragma unroll
  for (int kc = 0; kc < 8; ++kc) {
#pragma unroll
    for (int i = 0; i < 4; ++i) {
      bf16x8 a = *(const bf16x8*)(As + kc * 2048 + (16 * i + lr) * 32 + rchunk);
#pragma unroll
      for (int j = 0; j < 2; ++j)
        acc[i][j] = __builtin_amdgcn_mfma_f32_16x16x32_bf16(a, bb[j][kc], acc[i][j], 0, 0, 0);
    }
  }
  __syncthreads();  // all As reads complete; reuse As as C-staging
  // Cs: [64 rows][136 stride] u16 (272B rows: 16B-aligned, rows 4 dwords apart
  // -> scatter writes max 2-way bank aliasing = free per m136)
  unsigned short* Cs = (unsigned short*)As;
#pragma unroll
  for (int i = 0; i < 4; ++i)
#pragma unroll
    for (int j = 0; j < 2; ++j)
#pragma unroll
      for (int r = 0; r < 4; ++r)
        Cs[(16 * i + lq * 4 + r) * 136 + wn + 16 * j + lr] = f2bh(acc[i][j][r]);
  __syncthreads();
#pragma unroll
  for (int p = 0; p < 4; ++p) {
    int idx = p * 256 + t;
    int row = idx >> 4, c8 = idx & 15;
    uint4 v = *(const uint4*)(Cs + row * 136 + c8 * 8);
    *(uint4*)(G + fbase + (size_t)(n0 + row) * C_ + d0 + c8 * 8) = v;
  }
}

// ---------------- kernel 3: attention row sums + diagonal ------------------------
// R18 = R14 revert (best measured: 72.6us): 2-phase double-buffered pipeline,
// 32-row m-tiles, 2x16KB LDS, 4 blocks/CU. R15 (reuse-4) failed: regalloc
// wouldn't keep a[4][8] resident, occupancy 19%. R16 (counted-vmcnt ring) = null.
// R17 (32x32 MFMA) regressed: 8.4M bank conflicts + f32x16 scratch spills.
// Only change vs R14: __expf -> raw v_exp_f32 (Mt carries the log2e scale).
__global__ __launch_bounds__(256, 4) void k_attn(const bf16* __restrict__ G,
                                                 const bf16* __restrict__ Ft,
                                                 float* __restrict__ snn,
                                                 float* __restrict__ lsum) {
  __shared__ bf16 Ks[2][32 * 256];  // 2 x 16 KB double buffer; chunk kc at kc*1024
  int bid = blockIdx.x;
  int b = bid & 7, q = (bid >> 3) & 3, ntile = bid >> 5;
  int n0 = ntile * 128;
  int t = threadIdx.x, w = t >> 6, l = t & 63;
  int lr = l & 15, lq = l >> 4;
  int wrow = w * 32;
  const size_t gbase = (size_t)b * N_ * C_;

  bf16x8 a[2][8];
#pragma unroll
  for (int i = 0; i < 2; ++i)
#pragma unroll
    for (int kc = 0; kc < 8; ++kc)
      a[i][kc] = *(const bf16x8*)(G + gbase + (size_t)(n0 + wrow + 16 * i + lr) * C_ + kc * 32 + lq * 8);

  float part[8];
#pragma unroll
  for (int s = 0; s < 8; ++s) part[s] = 0.f;

  int m_base = q * 1024;
  bool has_diag = (q == (ntile >> 3));
  int dbase = (ntile & 7) * 4;

  // staging offsets: 4 x 16B per thread per 32-row tile (16KB = 1024 x 16B)
  int soff[4];
#pragma unroll
  for (int p = 0; p < 4; ++p) {
    int flat = p * 256 + t;
    int kc = flat >> 7;
    int r = (flat >> 2) & 31;
    int col8 = flat & 3;
    soff[p] = r * C_ + kc * 32 + ((col8 ^ ((r >> 1) & 3)) * 8);
  }
  int rchunk = (lq ^ ((lr >> 1) & 3)) * 8;

  // prologue: stage tile 0 into buf 0
#pragma unroll
  for (int p = 0; p < 4; ++p)
    async_ld16(Ft + gbase + (size_t)m_base * C_ + soff[p],
               (bf16*)Ks + (p * 256 + t) * 8);
  asm volatile("s_waitcnt vmcnt(0)" ::: "memory");
  __builtin_amdgcn_s_barrier();

  for (int it = 0; it < 32; ++it) {
    int cur = it & 1;
    if (it < 31) {
      int m0 = m_base + (it + 1) * 32;
#pragma unroll
      for (int p = 0; p < 4; ++p)
        async_ld16(Ft + gbase + (size_t)m0 * C_ + soff[p],
                   (bf16*)Ks + (cur ^ 1) * 8192 + (p * 256 + t) * 8);
    }
    const bf16* ks = (const bf16*)Ks + cur * 8192;
    f32x4 acc[2][2] = {};
#pragma unroll
    for (int kc = 0; kc < 8; ++kc) {
      bf16x8 b0 = *(const bf16x8*)(ks + kc * 1024 + lr * 32 + rchunk);
      bf16x8 b1 = *(const bf16x8*)(ks + kc * 1024 + (16 + lr) * 32 + rchunk);
      acc[0][0] = __builtin_amdgcn_mfma_f32_16x16x32_bf16(a[0][kc], b0, acc[0][0], 0, 0, 0);
      acc[1][0] = __builtin_amdgcn_mfma_f32_16x16x32_bf16(a[1][kc], b0, acc[1][0], 0, 0, 0);
      acc[0][1] = __builtin_amdgcn_mfma_f32_16x16x32_bf16(a[0][kc], b1, acc[0][1], 0, 0, 0);
      acc[1][1] = __builtin_amdgcn_mfma_f32_16x16x32_bf16(a[1][kc], b1, acc[1][1], 0, 0, 0);
    }
    bool dit = has_diag && ((it >> 2) == (ntile & 7));
#pragma unroll
    for (int i = 0; i < 2; ++i)
#pragma unroll
      for (int j = 0; j < 2; ++j)
#pragma unroll
        for (int r = 0; r < 4; ++r) {
          float e = __builtin_amdgcn_exp2f(acc[i][j][r]);  // logits carry log2e
          part[i * 4 + r] += e;
          if (dit) {
            int rloc = wrow + 16 * i + lq * 4 + r;
            int cloc = 16 * j + lr;
            if ((it - dbase) * 32 + cloc == rloc) snn[b * N_ + n0 + rloc] = e;
          }
        }
    if (it < 31) {
      asm volatile("s_waitcnt vmcnt(0)" ::: "memory");
      __builtin_amdgcn_s_barrier();
    }
  }

#pragma unroll
  for (int s = 0; s < 8; ++s) {
    float v = part[s];
    v += __shfl_xor(v, 1);
    v += __shfl_xor(v, 2);
    v += __shfl_xor(v, 4);
    v += __shfl_xor(v, 8);
    part[s] = v;
  }
  if (lr == 0) {
#pragma unroll
    for (int i = 0; i < 2; ++i)
#pragma unroll
      for (int r = 0; r < 4; ++r)
        lsum[((size_t)q * B_ + b) * N_ + n0 + wrow + 16 * i + lq * 4 + r] = part[i * 4 + r];
  }
}

// ---------------- kernel 4: out = F * snn/(sum_q lsum * (1+1e-8)) ----------------
// R18 re-block: 512 blocks, each owns (b, 64n) x all 256c. The 64 dd[n] divisors
// are computed ONCE per block into LDS (1KB of snn/lsum reads vs the old ~100MB
// of L2 re-reads: every thread used to re-read 8 float4 of lsum per 8 outputs).
// F/out streaming coalesced: wave reads 4 rows x 64B segments per instr.
__global__ __launch_bounds__(256) void k_scale(const void* __restrict__ Fv,
                                               const float* __restrict__ snn,
                                               const float* __restrict__ lsum,
                                               void* __restrict__ Outv) {
  __shared__ __align__(16) float dd_lds[64];
  bool f32 = wave_sniff_fp32((const unsigned short*)Fv);
  int bid = blockIdx.x;
  int b = bid >> 6, n0 = (bid & 63) * 64;
  int t = threadIdx.x;
  if (t < 64) {
    int n = n0 + t;
    float s = snn[(size_t)b * N_ + n];
    float ls = 0.f;
#pragma unroll
    for (int p = 0; p < 4; ++p) ls += lsum[((size_t)p * B_ + b) * N_ + n];
    dd_lds[t] = s / (ls * (1.0f + 1e-8f));
  }
  __syncthreads();
  const size_t fb = (size_t)b * C_ * N_;
  if (f32) {
    const float* F = (const float*)Fv;
    float* O = (float*)Outv;
#pragma unroll
    for (int p = 0; p < 16; ++p) {
      int idx = p * 256 + t;            // 4096 float4 units: 256c x 16 chunks
      int c = idx >> 4, ch = idx & 15;
      size_t off = fb + (size_t)c * N_ + n0 + ch * 4;
      float4 v = *(const float4*)(F + off);
      float4 d = *(const float4*)(&dd_lds[ch * 4]);
      float4 o;
      o.x = v.x * d.x; o.y = v.y * d.y; o.z = v.z * d.z; o.w = v.w * d.w;
      *(float4*)(O + off) = o;
    }
  } else {
    const unsigned short* F = (const unsigned short*)Fv;
    unsigned short* O = (unsigned short*)Outv;
#pragma unroll
    for (int p = 0; p < 8; ++p) {
      int idx = p * 256 + t;            // 2048 uint4 units: 256c x 8 chunks
      int c = idx >> 3, ch = idx & 7;
      size_t off = fb + (size_t)c * N_ + n0 + ch * 8;
      uint4 v = *(const uint4*)(F + off);
      u32 vv[4] = {v.x, v.y, v.z, v.w};
      u32 o[4];
#pragma unroll
      for (int k = 0; k < 4; ++k) {
        float lo = bh2f((unsigned short)(vv[k] & 0xffffu)) * dd_lds[ch * 8 + 2 * k];
        float hi = bh2f((unsigned short)(vv[k] >> 16)) * dd_lds[ch * 8 + 2 * k + 1];
        o[k] = ((u32)f2bh(hi) << 16) | f2bh(lo);
      }
      uint4 ov; ov.x = o[0]; ov.y = o[1]; ov.z = o[2]; ov.w = o[3];
      *(uint4*)(O + off) = ov;
    }
  }
}

extern "C" void kernel_launch(void* const* d_in, const int* in_sizes, int n_in,
                              void* d_out, int out_size, void* d_ws, size_t ws_size,
                              hipStream_t stream) {
  (void)in_sizes; (void)n_in; (void)out_size; (void)ws_size;
  const void* F = d_in[0];
  const void* Wq = d_in[1];
  const void* Wk = d_in[2];
  char* ws = (char*)d_ws;
  bf16* Ft = (bf16*)(ws);                         // 16 MiB
  bf16* G = (bf16*)(ws + (16u << 20));            // 16 MiB
  char* tail = ws + (32u << 20);
  float* snn = (float*)(tail);                    // 128 KiB
  float* lsum = (float*)(tail + 131072);          // 512 KiB (4 partials)
  bf16* Mt = (bf16*)(tail + 131072 + 524288);     // 128 KiB

  k_pre<<<256 + 2048, 256, 0, stream>>>(Wq, Wk, F, (unsigned short*)Mt, (unsigned short*)Ft);
  k_proj<<<dim3(N_ / 64, B_, 2), 256, 0, stream>>>(Ft, Mt, G);
  k_attn<<<1024, 256, 0, stream>>>(G, Ft, snn, lsum);
  k_scale<<<512, 256, 0, stream>>>(F, snn, lsum, d_out);
}